// Round 4
// baseline (326.522 us; speedup 1.0000x reference)
//
#include <hip/hip_runtime.h>

#define IMG_H 384
#define IMG_W 384
#define IMG_PIX (IMG_H * IMG_W)          // 147456
#define PIX4_PER_PLANE (IMG_PIX / 4)     // 36864

typedef float f32x4 __attribute__((ext_vector_type(4)));   // native vec for nontemporal builtins

// Fused GridMask: one kernel, one pass. Each thread owns one float4 (4
// consecutive pixels of one row; 384 % 4 == 0 so they never straddle rows)
// and computes its own coverage inline from the tiny (8x8) cell arrays,
// which are L1/L2-resident. x/out are streamed non-temporally (touched once,
// 453 MB total > L3). The x load is issued before the mask math so HBM
// latency overlaps the VALU work.
//
// Coverage semantics (must match reference exactly):
//   l = int(d * 0.6) (double trunc); gh = ceil(H/d); gw = ceil(W/d)
//   cell (a,b) active iff cell_active[a,b] > 0
//   ip = clip(a*d + off_i - 2, 0, H - l); rows [ip, ip+l)
//   jp = clip(b*d + off_j - 2, 0, W - l); cols [jp, jp+l)
//   pixel zeroed iff covered by any active cell; pass-through if flag <= 0.
// Since the window plus +/-2 jitter spans < 2d, only cells q-1..q+1 per axis
// can cover a pixel; for 4 pixels the b-range widens to [j0/d-1, (j0+3)/d+1].
__global__ void __launch_bounds__(256)
gridmask_fused(const f32x4* __restrict__ x,
               const int* __restrict__ cell_active,
               const int* __restrict__ off_i,
               const int* __restrict__ off_j,
               const int* __restrict__ d_ptr,
               const int* __restrict__ flag_ptr,
               f32x4* __restrict__ out) {
    int pix4 = blockIdx.x * blockDim.x + threadIdx.x;   // 0..36863 within plane
    long g   = (long)blockIdx.y * PIX4_PER_PLANE + pix4;

    f32x4 v = __builtin_nontemporal_load(&x[g]);        // issue stream load first

    int d    = d_ptr[0];
    int flag = flag_ptr[0];

    bool c0 = false, c1 = false, c2 = false, c3 = false;
    if (flag > 0 && d > 0) {
        int pix = pix4 << 2;
        int i   = pix / IMG_W;             // const divisor -> magic mul
        int j0  = pix - i * IMG_W;
        int l   = (int)((double)d * 0.6);  // match Python int(d*0.6)
        int gh  = (IMG_H + d - 1) / d;
        int gw  = (IMG_W + d - 1) / d;
        int qa  = i / d;
        int b_lo = j0 / d - 1;
        int b_hi = (j0 + 3) / d + 1;
        for (int a = qa - 1; a <= qa + 1; ++a) {
            if (a < 0 || a >= gh) continue;
            for (int b = b_lo; b <= b_hi; ++b) {
                if (b < 0 || b >= gw) continue;
                int idx = a * gw + b;
                if (cell_active[idx] <= 0) continue;
                int ip = min(max(a * d + off_i[idx] - 2, 0), IMG_H - l);
                if (i < ip || i >= ip + l) continue;
                int jp = min(max(b * d + off_j[idx] - 2, 0), IMG_W - l);
                int lo = jp, hi = jp + l;
                c0 |= (j0     >= lo) && (j0     < hi);
                c1 |= (j0 + 1 >= lo) && (j0 + 1 < hi);
                c2 |= (j0 + 2 >= lo) && (j0 + 2 < hi);
                c3 |= (j0 + 3 >= lo) && (j0 + 3 < hi);
            }
        }
    }

    f32x4 r;
    r.x = c0 ? 0.0f : v.x;
    r.y = c1 ? 0.0f : v.y;
    r.z = c2 ? 0.0f : v.z;
    r.w = c3 ? 0.0f : v.w;
    __builtin_nontemporal_store(r, &out[g]);
}

extern "C" void kernel_launch(void* const* d_in, const int* in_sizes, int n_in,
                              void* d_out, int out_size, void* d_ws, size_t ws_size,
                              hipStream_t stream) {
    const float* x           = (const float*)d_in[0];
    const int*   cell_active = (const int*)d_in[1];
    const int*   off_i       = (const int*)d_in[2];
    const int*   off_j       = (const int*)d_in[3];
    const int*   d_val       = (const int*)d_in[4];
    const int*   apply_flag  = (const int*)d_in[5];
    float*       out         = (float*)d_out;
    (void)d_ws; (void)ws_size;

    int planes = out_size / IMG_PIX;                 // 128*3 = 384
    dim3 grid(PIX4_PER_PLANE / 256, planes);         // (144, 384)
    gridmask_fused<<<grid, 256, 0, stream>>>(
        (const f32x4*)x, cell_active, off_i, off_j, d_val, apply_flag,
        (f32x4*)out);
}

// Round 5
// 77.623 us; speedup vs baseline: 4.2065x; 4.2065x over previous
//
#include <hip/hip_runtime.h>

#define IMG_H 384
#define IMG_W 384
#define IMG_PIX (IMG_H * IMG_W)          // 147456
#define PIX4_PER_PLANE (IMG_PIX / 4)     // 36864
#define MASK_WORDS (IMG_PIX / 64)        // 2304 uint64 = 18432 bytes

typedef float f32x4 __attribute__((ext_vector_type(4)));   // native vec for nontemporal builtins

// Kernel 1: build bit-packed mask into workspace (once per PIXEL — computing
// this inline per plane [round 4] blew the VALU budget 384x over and was
// latency-bound on the cell-metadata gather chain; see session journal).
// bit = 1  <=>  pixel covered by an active cell's square  <=>  output zeroed.
// Each wave (64 lanes) handles 64 consecutive columns of one row; lane 0
// writes the ballot word. 384 % 64 == 0 so waves never straddle rows.
__global__ void gridmask_build_mask(const int* __restrict__ cell_active,
                                    const int* __restrict__ off_i,
                                    const int* __restrict__ off_j,
                                    const int* __restrict__ d_ptr,
                                    const int* __restrict__ flag_ptr,
                                    unsigned long long* __restrict__ mask_words) {
    int pix = blockIdx.x * blockDim.x + threadIdx.x;
    if (pix >= IMG_PIX) return;
    int i = pix / IMG_W;
    int j = pix - i * IMG_W;

    int d    = d_ptr[0];
    int flag = flag_ptr[0];

    bool covered = false;
    if (flag > 0 && d > 0) {
        // Match Python: l = int(d * 0.6) with double arithmetic (truncation).
        int l  = (int)((double)d * 0.6);
        int gh = (IMG_H + d - 1) / d;
        int gw = (IMG_W + d - 1) / d;
        int qa = i / d;
        int qb = j / d;
        // Window is [clip(a*d + off - 2, 0, H-l), +l) with l + 4 <= d, so only
        // cells q-1..q+1 on each axis can cover pixel (i, j).
        for (int a = qa - 1; a <= qa + 1; ++a) {
            if (a < 0 || a >= gh) continue;
            for (int b = qb - 1; b <= qb + 1; ++b) {
                if (b < 0 || b >= gw) continue;
                int idx = a * gw + b;
                if (cell_active[idx] <= 0) continue;
                int ip = a * d + off_i[idx] - 2;
                ip = min(max(ip, 0), IMG_H - l);
                if (i < ip || i >= ip + l) continue;
                int jp = b * d + off_j[idx] - 2;
                jp = min(max(jp, 0), IMG_W - l);
                if (j >= jp && j < jp + l) covered = true;
            }
        }
    }

    unsigned long long bal = __ballot(covered);
    if ((threadIdx.x & 63) == 0) {
        mask_words[pix >> 6] = bal;   // pix>>6 == row*6 + j0/64 (384 = 6*64)
    }
}

// Kernel 2: out = x masked. 2D grid: blockIdx.y = plane (b*c), blockIdx.x
// covers one 147456-pixel plane in float4s. One float4 per thread — no loop,
// no modulo. Mask words (18 KB) are L1/L2-resident; x/out are streamed with
// non-temporal hints (touched exactly once, 453 MB total > L3).
// Measured at 6.2 TB/s = 98.5% of the float4-copy ceiling (m13: 6.29 TB/s).
__global__ void __launch_bounds__(256)
gridmask_apply(const f32x4* __restrict__ x,
               const unsigned long long* __restrict__ mask_words,
               f32x4* __restrict__ out) {
    int pix4 = blockIdx.x * blockDim.x + threadIdx.x;   // 0..36863 within plane
    long g   = (long)blockIdx.y * PIX4_PER_PLANE + pix4;
    int pix  = pix4 << 2;

    unsigned long long word = mask_words[pix >> 6];
    int sh = pix & 63;                                   // aligned to 4, <= 60

    f32x4 v = __builtin_nontemporal_load(&x[g]);
    f32x4 r;
    r.x = ((word >> (sh + 0)) & 1ull) ? 0.0f : v.x;
    r.y = ((word >> (sh + 1)) & 1ull) ? 0.0f : v.y;
    r.z = ((word >> (sh + 2)) & 1ull) ? 0.0f : v.z;
    r.w = ((word >> (sh + 3)) & 1ull) ? 0.0f : v.w;
    __builtin_nontemporal_store(r, &out[g]);
}

extern "C" void kernel_launch(void* const* d_in, const int* in_sizes, int n_in,
                              void* d_out, int out_size, void* d_ws, size_t ws_size,
                              hipStream_t stream) {
    const float* x           = (const float*)d_in[0];
    const int*   cell_active = (const int*)d_in[1];
    const int*   off_i       = (const int*)d_in[2];
    const int*   off_j       = (const int*)d_in[3];
    const int*   d_val       = (const int*)d_in[4];
    const int*   apply_flag  = (const int*)d_in[5];
    float*       out         = (float*)d_out;

    unsigned long long* mask_words = (unsigned long long*)d_ws;  // 18432 bytes

    // Kernel 1: 147456 pixels, 256 threads/block.
    int blocks1 = (IMG_PIX + 255) / 256;
    gridmask_build_mask<<<blocks1, 256, 0, stream>>>(
        cell_active, off_i, off_j, d_val, apply_flag, mask_words);

    // Kernel 2: one float4 per thread over [planes, 36864] grid.
    int planes = out_size / IMG_PIX;                 // 128*3 = 384
    dim3 grid2(PIX4_PER_PLANE / 256, planes);        // (144, 384)
    gridmask_apply<<<grid2, 256, 0, stream>>>(
        (const f32x4*)x, mask_words, (f32x4*)out);
}